// Round 1
// baseline (251.286 us; speedup 1.0000x reference)
//
#include <hip/hip_runtime.h>
#include <math.h>

// PhysQuadModel rollout: B independent envs, N sequential RK4 steps.
// Key simplifications (exact w.r.t. the reference math):
//  - omega_dot is multiplied by 0.0 in the reference -> omega constant, tau dead.
//  - quat kept in registers across steps (per-step so3 round trip is identity).
//  - quat_rotate(q,(0,0,T)) = T * third column of R.
// One thread per environment; compute-latency bound (only 256 waves total).

namespace {
constexpr float DT_  = 0.01f;
constexpr float G_   = 9.81f;
constexpr float TTW_ = 1.8f;
constexpr float M_   = 0.033f;
constexpr float KT_  = 3.72e-08f;
constexpr float EPS_ = 1e-6f;
}

__global__ __launch_bounds__(64)
void quad_rollout_kernel(const float* __restrict__ x0,
                         const float* __restrict__ u_seq,
                         float* __restrict__ out,
                         int B, int N)
{
    int b = blockIdx.x * 64 + threadIdx.x;
    if (b >= B) return;

    const float* xs = x0 + (size_t)b * 12;
    float px = xs[0], py = xs[1], pz = xs[2];
    float vx = xs[3], vy = xs[4], vz = xs[5];
    float rx = xs[6], ry = xs[7], rz = xs[8];
    float ox = xs[9], oy = xs[10], oz = xs[11];

    // axis-angle -> quat (once; afterwards quat lives in registers)
    float ang = sqrtf(rx*rx + ry*ry + rz*rz);
    float hf  = 0.5f * ang;
    float so;
    if (ang < EPS_) so = 0.5f - ang*ang*(1.0f/48.0f);
    else            so = sinf(hf) / ang;
    float qx = rx*so, qy = ry*so, qz = rz*so, qw = cosf(hf);

    const float dt      = DT_;
    const float T_MAX   = TTW_ * M_ * G_;
    const float invTMAX = 1.0f / T_MAX;
    const float TACC    = TTW_ * G_;   // T_MAX / M

    const float4* __restrict__ up = (const float4*)u_seq + (size_t)b * N;
    float*        __restrict__ op = out + (size_t)b * N * 12;

    for (int t = 0; t < N; ++t) {
        float4 u = up[t];
        float w2 = u.x*u.x + u.y*u.y + u.z*u.z + u.w*u.w;
        float Tn = KT_ * w2 * invTMAX;
        Tn = fminf(fmaxf(Tn, 0.0f), 1.0f);
        float Ta = Tn * TACC;          // thrust acceleration magnitude

        // ---- stage 1 (at q) ----
        float a1x = Ta * (2.0f*(qw*qy + qx*qz));
        float a1y = Ta * (2.0f*(qy*qz - qw*qx));
        float a1z = Ta * (1.0f - 2.0f*(qx*qx + qy*qy)) - G_;
        float d1x = 0.5f*(qw*ox + (qy*oz - qz*oy));
        float d1y = 0.5f*(qw*oy + (qz*ox - qx*oz));
        float d1z = 0.5f*(qw*oz + (qx*oy - qy*ox));
        float d1w = -0.5f*(qx*ox + qy*oy + qz*oz);

        // ---- stage 2 (at normalize(q + 0.5 dt qd1)) ----
        float q2x = qx + 0.5f*dt*d1x, q2y = qy + 0.5f*dt*d1y;
        float q2z = qz + 0.5f*dt*d1z, q2w = qw + 0.5f*dt*d1w;
        float inv2 = 1.0f / sqrtf(q2x*q2x + q2y*q2y + q2z*q2z + q2w*q2w);
        q2x *= inv2; q2y *= inv2; q2z *= inv2; q2w *= inv2;
        float a2x = Ta * (2.0f*(q2w*q2y + q2x*q2z));
        float a2y = Ta * (2.0f*(q2y*q2z - q2w*q2x));
        float a2z = Ta * (1.0f - 2.0f*(q2x*q2x + q2y*q2y)) - G_;
        float d2x = 0.5f*(q2w*ox + (q2y*oz - q2z*oy));
        float d2y = 0.5f*(q2w*oy + (q2z*ox - q2x*oz));
        float d2z = 0.5f*(q2w*oz + (q2x*oy - q2y*ox));
        float d2w = -0.5f*(q2x*ox + q2y*oy + q2z*oz);

        // ---- stage 3 (at normalize(q + 0.5 dt qd2)) ----
        float q3x = qx + 0.5f*dt*d2x, q3y = qy + 0.5f*dt*d2y;
        float q3z = qz + 0.5f*dt*d2z, q3w = qw + 0.5f*dt*d2w;
        float inv3 = 1.0f / sqrtf(q3x*q3x + q3y*q3y + q3z*q3z + q3w*q3w);
        q3x *= inv3; q3y *= inv3; q3z *= inv3; q3w *= inv3;
        float a3x = Ta * (2.0f*(q3w*q3y + q3x*q3z));
        float a3y = Ta * (2.0f*(q3y*q3z - q3w*q3x));
        float a3z = Ta * (1.0f - 2.0f*(q3x*q3x + q3y*q3y)) - G_;
        float d3x = 0.5f*(q3w*ox + (q3y*oz - q3z*oy));
        float d3y = 0.5f*(q3w*oy + (q3z*ox - q3x*oz));
        float d3z = 0.5f*(q3w*oz + (q3x*oy - q3y*ox));
        float d3w = -0.5f*(q3x*ox + q3y*oy + q3z*oz);

        // ---- stage 4 (at normalize(q + dt qd3)) ----
        float q4x = qx + dt*d3x, q4y = qy + dt*d3y;
        float q4z = qz + dt*d3z, q4w = qw + dt*d3w;
        float inv4 = 1.0f / sqrtf(q4x*q4x + q4y*q4y + q4z*q4z + q4w*q4w);
        q4x *= inv4; q4y *= inv4; q4z *= inv4; q4w *= inv4;
        float a4x = Ta * (2.0f*(q4w*q4y + q4x*q4z));
        float a4y = Ta * (2.0f*(q4y*q4z - q4w*q4x));
        float a4z = Ta * (1.0f - 2.0f*(q4x*q4x + q4y*q4y)) - G_;
        float d4x = 0.5f*(q4w*ox + (q4y*oz - q4z*oy));
        float d4y = 0.5f*(q4w*oy + (q4z*ox - q4x*oz));
        float d4z = 0.5f*(q4w*oz + (q4x*oy - q4y*ox));
        float d4w = -0.5f*(q4x*ox + q4y*oy + q4z*oz);

        // ---- combine ----
        const float s6 = dt * (1.0f/6.0f);
        // pos: v1=vel, v2=vel+0.5dt a1, v3=vel+0.5dt a2, v4=vel+dt a3
        px += s6 * (6.0f*vx + dt*(a1x + a2x + a3x));
        py += s6 * (6.0f*vy + dt*(a1y + a2y + a3y));
        pz += s6 * (6.0f*vz + dt*(a1z + a2z + a3z));
        vx += s6 * (a1x + 2.0f*a2x + 2.0f*a3x + a4x);
        vy += s6 * (a1y + 2.0f*a2y + 2.0f*a3y + a4y);
        vz += s6 * (a1z + 2.0f*a2z + 2.0f*a3z + a4z);
        float qnx = qx + s6 * (d1x + 2.0f*d2x + 2.0f*d3x + d4x);
        float qny = qy + s6 * (d1y + 2.0f*d2y + 2.0f*d3y + d4y);
        float qnz = qz + s6 * (d1z + 2.0f*d2z + 2.0f*d3z + d4z);
        float qnw = qw + s6 * (d1w + 2.0f*d2w + 2.0f*d3w + d4w);
        float invn = 1.0f / sqrtf(qnx*qnx + qny*qny + qnz*qnz + qnw*qnw);
        qx = qnx*invn; qy = qny*invn; qz = qnz*invn; qw = qnw*invn;

        // ---- quat -> so3 for output (sin(half) == |qv| for normalized q) ----
        float n3   = sqrtf(qx*qx + qy*qy + qz*qz);
        float angs = 2.0f * atan2f(n3, qw);
        float scl  = angs / fmaxf(n3, 1e-12f);
        float srx = qx*scl, sry = qy*scl, srz = qz*scl;

        float4* o4 = (float4*)(op + (size_t)t * 12);
        o4[0] = make_float4(px, py, pz, vx);
        o4[1] = make_float4(vy, vz, srx, sry);
        o4[2] = make_float4(srz, ox, oy, oz);
    }
}

extern "C" void kernel_launch(void* const* d_in, const int* in_sizes, int n_in,
                              void* d_out, int out_size, void* d_ws, size_t ws_size,
                              hipStream_t stream) {
    const float* x0    = (const float*)d_in[0];
    const float* u_seq = (const float*)d_in[1];
    float* out = (float*)d_out;
    int B = in_sizes[0] / 12;
    int N = in_sizes[1] / (B * 4);
    dim3 grid((B + 63) / 64), block(64);
    hipLaunchKernelGGL(quad_rollout_kernel, grid, block, 0, stream,
                       x0, u_seq, out, B, N);
}

// Round 2
// 101.023 us; speedup vs baseline: 2.4874x; 2.4874x over previous
//
#include <hip/hip_runtime.h>
#include <math.h>

// PhysQuadModel rollout, fully parallel over (env, time).
//
// Key algebra (exact w.r.t. the reference math):
//  - omega_dot == 0 in the reference -> omega constant -> quat_derivative is a
//    fixed linear map q -> 0.5 * q (x) w, w = (omega, 0).
//  - Each RK4 stage quat is q (x) n_i for fixed unit quats n_i(omega, dt), so
//    one full RK4 step is q_{t+1} = q_t (x) P (fixed unit quat per env).
//    => q_t = q0 (x) (u sin(t*phi), cos(t*phi))  (closed form).
//  - Stage thrust dirs: R(q_t (x) n_i) e3 = R(q_t) c_i, c_i = R(n_i) e3 fixed.
//    vel/pos updates reduce via Rodrigues about the fixed axis u to prefix sums
//    of 6 scalars: {Ta_k, Ta_k cos(k*th), Ta_k sin(k*th)} and k-weighted ones.
//  - Every output row t is then independent: one wave per env, 4 rows/lane,
//    wave-level shuffle scan. 16384 waves -> occupancy instead of 256 waves.

namespace {
constexpr float DT_  = 0.01f;
constexpr float G_   = 9.81f;
constexpr float TTW_ = 1.8f;
constexpr float M_   = 0.033f;
constexpr float KT_  = 3.72e-08f;
constexpr float EPS_ = 1e-6f;
}

__device__ __forceinline__ float4 qmul(float4 p, float4 q) {
    return make_float4(
        p.w*q.x + q.w*p.x + (p.y*q.z - p.z*q.y),
        p.w*q.y + q.w*p.y + (p.z*q.x - p.x*q.z),
        p.w*q.z + q.w*p.z + (p.x*q.y - p.y*q.x),
        p.w*q.w - (p.x*q.x + p.y*q.y + p.z*q.z));
}

__device__ __forceinline__ float4 qnormalize(float4 q) {
    float inv = 1.0f / sqrtf(q.x*q.x + q.y*q.y + q.z*q.z + q.w*q.w);
    return make_float4(q.x*inv, q.y*inv, q.z*inv, q.w*inv);
}

// m = n (x) w,  w = (wx,wy,wz,0) pure
__device__ __forceinline__ float4 qmul_pure(float4 n, float wx, float wy, float wz) {
    return make_float4(
        n.w*wx + (n.y*wz - n.z*wy),
        n.w*wy + (n.z*wx - n.x*wz),
        n.w*wz + (n.x*wy - n.y*wx),
        -(n.x*wx + n.y*wy + n.z*wz));
}

__global__ __launch_bounds__(256)
void quad_scan_kernel(const float* __restrict__ x0,
                      const float4* __restrict__ u_seq,
                      float* __restrict__ out,
                      int B, int N)
{
    const int wave = threadIdx.x >> 6;
    const int lane = threadIdx.x & 63;
    const int env  = blockIdx.x * 4 + wave;
    if (env >= B) return;

    const float* xs = x0 + (size_t)env * 12;
    const float px0 = xs[0], py0 = xs[1], pz0 = xs[2];
    const float vx0 = xs[3], vy0 = xs[4], vz0 = xs[5];
    const float rx  = xs[6], ry  = xs[7], rz  = xs[8];
    const float ox  = xs[9], oy  = xs[10], oz = xs[11];

    // ---- q0 from axis-angle (matches reference) ----
    float ang = sqrtf(rx*rx + ry*ry + rz*rz);
    float hf  = 0.5f * ang;
    float sh, ch;
    sincosf(hf, &sh, &ch);
    float so = (ang < EPS_) ? (0.5f - ang*ang*(1.0f/48.0f)) : (sh / ang);
    float4 q0 = make_float4(rx*so, ry*so, rz*so, ch);

    // ---- fixed RK4 stage quats (right factors), per env ----
    const float dt = DT_, dt4 = 0.25f*dt, dt2 = 0.5f*dt, dt12 = dt*(1.0f/12.0f);
    float4 n2 = qnormalize(make_float4(dt4*ox, dt4*oy, dt4*oz, 1.0f));
    float4 m2 = qmul_pure(n2, ox, oy, oz);
    float4 n3 = qnormalize(make_float4(dt4*m2.x, dt4*m2.y, dt4*m2.z, 1.0f + dt4*m2.w));
    float4 m3 = qmul_pure(n3, ox, oy, oz);
    float4 n4 = qnormalize(make_float4(dt2*m3.x, dt2*m3.y, dt2*m3.z, 1.0f + dt2*m3.w));
    float4 m4 = qmul_pure(n4, ox, oy, oz);
    float4 P  = qnormalize(make_float4(
        dt12*(ox + 2.0f*m2.x + 2.0f*m3.x + m4.x),
        dt12*(oy + 2.0f*m2.y + 2.0f*m3.y + m4.y),
        dt12*(oz + 2.0f*m2.z + 2.0f*m3.z + m4.z),
        1.0f + dt12*(2.0f*m2.w + 2.0f*m3.w + m4.w)));

    // stage thrust columns c_i = R(n_i) e3 ; c1 = e3
    #define COL3X(q) (2.0f*((q).x*(q).z + (q).w*(q).y))
    #define COL3Y(q) (2.0f*((q).y*(q).z - (q).w*(q).x))
    #define COL3Z(q) (1.0f - 2.0f*((q).x*(q).x + (q).y*(q).y))
    float c2x = COL3X(n2), c2y = COL3Y(n2), c2z = COL3Z(n2);
    float c3x = COL3X(n3), c3y = COL3Y(n3), c3z = COL3Z(n3);
    float c4x = COL3X(n4), c4y = COL3Y(n4), c4z = COL3Z(n4);
    // Cv = c1 + 2c2 + 2c3 + c4 ; Cp = c1 + c2 + c3
    float Cvx = 2.0f*(c2x + c3x) + c4x;
    float Cvy = 2.0f*(c2y + c3y) + c4y;
    float Cvz = 1.0f + 2.0f*(c2z + c3z) + c4z;
    float Cpx = c2x + c3x;
    float Cpy = c2y + c3y;
    float Cpz = 1.0f + c2z + c3z;

    // axis / half-angle of P
    float un   = sqrtf(P.x*P.x + P.y*P.y + P.z*P.z);
    float phih = atan2f(un, P.w);
    float theta = 2.0f * phih;
    float ux, uy, uz;
    if (un > 1e-20f) { float iu = 1.0f/un; ux = P.x*iu; uy = P.y*iu; uz = P.z*iu; }
    else             { ux = 0.0f; uy = 0.0f; uz = 1.0f; }

    // Rodrigues decomposition about u for Cv and Cp
    float dv = ux*Cvx + uy*Cvy + uz*Cvz;
    float Cv_px = dv*ux, Cv_py = dv*uy, Cv_pz = dv*uz;           // parallel
    float Cv_ex = Cvx - Cv_px, Cv_ey = Cvy - Cv_py, Cv_ez = Cvz - Cv_pz; // perp
    float Cv_cx = uy*Cvz - uz*Cvy, Cv_cy = uz*Cvx - ux*Cvz, Cv_cz = ux*Cvy - uy*Cvx; // u x Cv
    float dp = ux*Cpx + uy*Cpy + uz*Cpz;
    float Cp_px = dp*ux, Cp_py = dp*uy, Cp_pz = dp*uz;
    float Cp_ex = Cpx - Cp_px, Cp_ey = Cpy - Cp_py, Cp_ez = Cpz - Cp_pz;
    float Cp_cx = uy*Cpz - uz*Cpy, Cp_cy = uz*Cpx - ux*Cpz, Cp_cz = ux*Cpy - uy*Cpx;

    // rotation matrix of q0
    float qx = q0.x, qy = q0.y, qz = q0.z, qw = q0.w;
    float r00 = 1.0f - 2.0f*(qy*qy + qz*qz), r01 = 2.0f*(qx*qy - qw*qz), r02 = 2.0f*(qx*qz + qw*qy);
    float r10 = 2.0f*(qx*qy + qw*qz), r11 = 1.0f - 2.0f*(qx*qx + qz*qz), r12 = 2.0f*(qy*qz - qw*qx);
    float r20 = 2.0f*(qx*qz - qw*qy), r21 = 2.0f*(qy*qz + qw*qx), r22 = 1.0f - 2.0f*(qx*qx + qy*qy);

    const float T_MAX   = TTW_ * M_ * G_;
    const float invTMAX = 1.0f / T_MAX;
    const float TACC    = TTW_ * G_;   // T_MAX / M

    // ---- per-lane local contributions + serial inclusive sums (4 steps/lane) ----
    const float4* __restrict__ up = u_seq + (size_t)env * N;
    float la[4], lb[4], lc[4], lA[4], lB[4], lC[4];
    float sa = 0.f, sb = 0.f, sc = 0.f, sA = 0.f, sB = 0.f, sC = 0.f;
    const int k0 = lane * 4;
    #pragma unroll
    for (int j = 0; j < 4; ++j) {
        int k = k0 + j;
        float Ta = 0.f, cs = 1.f, sn = 0.f, kf = (float)k;
        if (k < N) {
            float4 u = up[k];
            float w2 = u.x*u.x + u.y*u.y + u.z*u.z + u.w*u.w;
            float Tn = fminf(fmaxf(KT_*w2*invTMAX, 0.0f), 1.0f);
            Ta = Tn * TACC;
            sincosf(theta * kf, &sn, &cs);
        }
        sa += Ta;        sb += Ta*cs;     sc += Ta*sn;
        sA += kf*Ta;     sB += kf*Ta*cs;  sC += kf*Ta*sn;
        la[j] = sa; lb[j] = sb; lc[j] = sc;
        lA[j] = sA; lB[j] = sB; lC[j] = sC;
    }

    // ---- wave-wide inclusive scan of lane totals (Hillis-Steele) ----
    float ta = sa, tb = sb, tc = sc, tA = sA, tB = sB, tC = sC;
    #pragma unroll
    for (int d = 1; d < 64; d <<= 1) {
        float xa = __shfl_up(ta, d), xb = __shfl_up(tb, d), xc = __shfl_up(tc, d);
        float xA = __shfl_up(tA, d), xB = __shfl_up(tB, d), xC = __shfl_up(tC, d);
        if (lane >= d) { ta += xa; tb += xb; tc += xc; tA += xA; tB += xB; tC += xC; }
    }
    const float ba = ta - sa, bb = tb - sb, bc = tc - sc;   // exclusive bases
    const float bA = tA - sA, bB = tB - sB, bC = tC - sC;

    // ---- emit 4 output rows per lane ----
    float* __restrict__ op = out + (size_t)env * N * 12;
    const float dt6  = dt * (1.0f/6.0f);
    const float dt26 = dt * dt * (1.0f/6.0f);
    #pragma unroll
    for (int j = 0; j < 4; ++j) {
        int k = k0 + j;
        if (k >= N) break;
        float Ea = ba + la[j], Eb = bb + lb[j], Ec = bc + lc[j];
        float EA = bA + lA[j], EB = bB + lB[j], EC = bC + lC[j];
        float tf = (float)(k + 1);

        // velocity combo vector (rotate once by R(q0) at the end)
        float Vvx = Cv_px*Ea + Cv_ex*Eb + Cv_cx*Ec;
        float Vvy = Cv_py*Ea + Cv_ey*Eb + Cv_cy*Ec;
        float Vvz = Cv_pz*Ea + Cv_ez*Eb + Cv_cz*Ec;
        // position combo vector
        float cw = tf - 1.0f;
        float Wa = cw*Ea - EA, Wb = cw*Eb - EB, Wc = cw*Ec - EC;
        float Vpx = Cv_px*Wa + Cv_ex*Wb + Cv_cx*Wc + Cp_px*Ea + Cp_ex*Eb + Cp_cx*Ec;
        float Vpy = Cv_py*Wa + Cv_ey*Wb + Cv_cy*Wc + Cp_py*Ea + Cp_ey*Eb + Cp_cy*Ec;
        float Vpz = Cv_pz*Wa + Cv_ez*Wb + Cv_cz*Wc + Cp_pz*Ea + Cp_ez*Eb + Cp_cz*Ec;

        float rvx = r00*Vvx + r01*Vvy + r02*Vvz;
        float rvy = r10*Vvx + r11*Vvy + r12*Vvz;
        float rvz = r20*Vvx + r21*Vvy + r22*Vvz;
        float rpx = r00*Vpx + r01*Vpy + r02*Vpz;
        float rpy = r10*Vpx + r11*Vpy + r12*Vpz;
        float rpz = r20*Vpx + r21*Vpy + r22*Vpz;

        float velx = vx0 + dt6*rvx;
        float vely = vy0 + dt6*rvy;
        float velz = vz0 + dt6*rvz - tf*dt*G_;
        float posx = px0 + tf*dt*vx0 + dt26*rpx;
        float posy = py0 + tf*dt*vy0 + dt26*rpy;
        float posz = pz0 + tf*dt*vz0 + dt26*rpz - 0.5f*tf*tf*dt*dt*G_;

        // q_t = q0 (x) P^t,  P^t = (u sin(t*phih), cos(t*phih))
        float st, ct;
        sincosf(phih * tf, &st, &ct);
        float4 Pt = make_float4(ux*st, uy*st, uz*st, ct);
        float4 qt = qmul(q0, Pt);

        // quat -> so3 (sin(half) == |qv| for unit q)
        float nv  = sqrtf(qt.x*qt.x + qt.y*qt.y + qt.z*qt.z);
        float scl = 2.0f * atan2f(nv, qt.w) / fmaxf(nv, 1e-12f);
        float srx = qt.x*scl, sry = qt.y*scl, srz = qt.z*scl;

        float4* o4 = (float4*)(op + (size_t)k * 12);
        o4[0] = make_float4(posx, posy, posz, velx);
        o4[1] = make_float4(vely, velz, srx, sry);
        o4[2] = make_float4(srz, ox, oy, oz);
    }
}

extern "C" void kernel_launch(void* const* d_in, const int* in_sizes, int n_in,
                              void* d_out, int out_size, void* d_ws, size_t ws_size,
                              hipStream_t stream) {
    const float*  x0    = (const float*)d_in[0];
    const float4* u_seq = (const float4*)d_in[1];
    float* out = (float*)d_out;
    int B = in_sizes[0] / 12;
    int N = in_sizes[1] / (B * 4);
    dim3 grid((B + 3) / 4), block(256);
    hipLaunchKernelGGL(quad_scan_kernel, grid, block, 0, stream,
                       x0, u_seq, out, B, N);
}